// Round 5
// baseline (1059.742 us; speedup 1.0000x reference)
//
#include <hip/hip_runtime.h>
#include <cmath>

#define NB 16
#define TSEQ 1024
#define DIN 16
#define DM 512
#define DFFN 2048
#define NLAYERS 4
#define DOUTN 3
#define ROWS (NB*TSEQ)   /* 16384 */

typedef unsigned short u16;
typedef short bf16x8 __attribute__((ext_vector_type(8)));
typedef u16   u16x4  __attribute__((ext_vector_type(4)));
typedef float f32x4  __attribute__((ext_vector_type(4)));

__device__ __forceinline__ float b2f(u16 v) { return __uint_as_float((unsigned)v << 16); }
__device__ __forceinline__ u16 f2b(float f) {
    unsigned u = __float_as_uint(f);
    return (u16)((u + 0x7FFFu + ((u >> 16) & 1u)) >> 16);
}

#define GLL(gp, lp) __builtin_amdgcn_global_load_lds( \
    (const __attribute__((address_space(1))) unsigned int*)(gp), \
    (__attribute__((address_space(3))) unsigned int*)(lp), 16, 0, 0)

typedef __attribute__((address_space(3))) const u16 lds_cu16;

// asm LDS read: compiler can't see a vmcnt dependency -> no injected drains.
// Discipline (rule 18): consumer side does lgkmcnt(0) + sched_barrier(0).
__device__ __forceinline__ bf16x8 ds_read16(const u16* p) {
    bf16x8 r;
    asm volatile("ds_read_b128 %0, %1" : "=v"(r) : "v"((lds_cu16*)p));
    return r;
}

#define FENCE() asm volatile("" ::: "memory")
#define BARR()  do { FENCE(); __builtin_amdgcn_s_barrier(); FENCE(); } while (0)
#define WAITVM4() asm volatile("s_waitcnt vmcnt(4)" ::: "memory")
#define WAITVM0() asm volatile("s_waitcnt vmcnt(0)" ::: "memory")
#define WAITLGKM0() do { asm volatile("s_waitcnt lgkmcnt(0)" ::: "memory"); \
                         __builtin_amdgcn_sched_barrier(0); } while (0)

// ------------------------------------------------- weight transpose + cast
__global__ __launch_bounds__(256) void transpose_cast(
    const float* __restrict__ in, u16* __restrict__ out,
    int K, int N, size_t in_lstride, size_t out_lstride)
{
    in  += (size_t)blockIdx.z * in_lstride;
    out += (size_t)blockIdx.z * out_lstride;
    __shared__ float t[32][33];
    int bk = blockIdx.x * 32, bn = blockIdx.y * 32;
    int x = threadIdx.x & 31, y = threadIdx.x >> 5;
    #pragma unroll
    for (int i = 0; i < 32; i += 8)
        t[y + i][x] = in[(size_t)(bk + y + i) * N + bn + x];
    __syncthreads();
    #pragma unroll
    for (int i = 0; i < 32; i += 8)
        out[(size_t)(bn + y + i) * K + bk + x] = f2b(t[x][y + i]);
}

// ------------------------------------------------- encode (bf16 out)
__global__ __launch_bounds__(128) void encode_kernel(
    const float* __restrict__ x, const int* __restrict__ pad,
    const float* __restrict__ W, const float* __restrict__ b,
    u16* __restrict__ h)
{
    int row = blockIdx.x;
    int t   = row & (TSEQ - 1);
    int c   = threadIdx.x * 4;
    float acc[4];
    #pragma unroll
    for (int j = 0; j < 4; ++j) acc[j] = b[c + j];
    const float* xr = x + (size_t)row * DIN;
    #pragma unroll
    for (int k = 0; k < DIN; ++k) {
        float xv = xr[k];
        const float* wr = W + (size_t)k * DM + c;
        #pragma unroll
        for (int j = 0; j < 4; ++j) acc[j] += xv * wr[j];
    }
    const float s = 22.62741699796952f;
    bool has_pe = (pad[row] != 0);
    u16x4 o;
    #pragma unroll
    for (int j = 0; j < 4; ++j) {
        acc[j] *= s;
        if (has_pe) {
            int d = c + j;
            float base = (float)t * powf(10000.0f, -(float)d * (1.0f/512.0f));
            acc[j] += ((d & 1) == 0) ? sinf(base) : cosf(base);
        }
        o[j] = f2b(acc[j]);
    }
    *(u16x4*)&h[(size_t)row * DM + c] = o;
}

// ------------------------------------------------- 128x128 MFMA GEMM (m97, proven)
template<int BIAS, int RELU>
__global__ __launch_bounds__(256) void gemm_bf16(
    const u16* __restrict__ A, const u16* __restrict__ Bt,
    const float* __restrict__ bias, u16* __restrict__ C,
    int M, int N, int K)
{
    __shared__ u16 As[128 * 32];
    __shared__ u16 Bs[128 * 32];
    const int tid  = threadIdx.x;
    const int lane = tid & 63;
    const int wid  = tid >> 6;
    const int wr   = wid >> 1, wc = wid & 1;
    const int bm   = blockIdx.x * 128;
    const int bn   = blockIdx.y * 128;

    const int srow = lane >> 2;
    const int scol = (lane & 3) * 8;
    const u16* Ag0 = A  + (size_t)(bm + wid * 32 + srow) * K + scol;
    const u16* Ag1 = Ag0 + (size_t)16 * K;
    const u16* Bg0 = Bt + (size_t)(bn + wid * 32 + srow) * K + scol;
    const u16* Bg1 = Bg0 + (size_t)16 * K;
    u16* Al = As + wid * 1024;
    u16* Bl = Bs + wid * 1024;

    f32x4 acc[4][4];
    #pragma unroll
    for (int m = 0; m < 4; ++m)
        #pragma unroll
        for (int n = 0; n < 4; ++n)
            acc[m][n] = (f32x4){0.f, 0.f, 0.f, 0.f};

    const int fr = lane & 15;
    const int fk = (lane >> 4) * 8;

    for (int k0 = 0; k0 < K; k0 += 32) {
        GLL(Ag0 + k0, Al);
        GLL(Ag1 + k0, Al + 512);
        GLL(Bg0 + k0, Bl);
        GLL(Bg1 + k0, Bl + 512);
        __syncthreads();
        bf16x8 a[4], b[4];
        #pragma unroll
        for (int m = 0; m < 4; ++m)
            a[m] = *(const bf16x8*)(As + (size_t)(wr * 64 + m * 16 + fr) * 32 + fk);
        #pragma unroll
        for (int n = 0; n < 4; ++n)
            b[n] = *(const bf16x8*)(Bs + (size_t)(wc * 64 + n * 16 + fr) * 32 + fk);
        #pragma unroll
        for (int m = 0; m < 4; ++m)
            #pragma unroll
            for (int n = 0; n < 4; ++n)
                acc[m][n] = __builtin_amdgcn_mfma_f32_16x16x32_bf16(a[m], b[n], acc[m][n], 0, 0, 0);
        __syncthreads();
    }

    float bb[4] = {0.f, 0.f, 0.f, 0.f};
    if (BIAS) {
        #pragma unroll
        for (int n = 0; n < 4; ++n) bb[n] = bias[bn + wc * 64 + n * 16 + fr];
    }
    #pragma unroll
    for (int m = 0; m < 4; ++m) {
        #pragma unroll
        for (int n = 0; n < 4; ++n) {
            int col = bn + wc * 64 + n * 16 + fr;
            #pragma unroll
            for (int j = 0; j < 4; ++j) {
                int row = bm + wr * 64 + m * 16 + ((lane >> 4) << 2) + j;
                float v = acc[m][n][j];
                if (BIAS) v += bb[n];
                if (RELU) v = fmaxf(v, 0.f);
                C[(size_t)row * N + col] = f2b(v);
            }
        }
    }
}

// ------------------------------------------------- 8-phase 256x256 MFMA GEMM
__device__ __forceinline__ void stage2(const u16* g, const u16* l, int K) {
    GLL(g, l);
    GLL(g + (size_t)64 * K, l + 4096);
}

__device__ __forceinline__ void lda_half(bf16x8* a, const u16* sb, int wr, int mh, int fr, int kq) {
    #pragma unroll
    for (int m = 0; m < 4; ++m) {
        int row = wr * 128 + (mh * 4 + m) * 16 + fr;
        int sw = (row & 4) << 2;
        #pragma unroll
        for (int ks = 0; ks < 2; ++ks)
            a[(mh * 4 + m) * 2 + ks] = ds_read16(sb + row * 64 + ((ks * 32 + kq) ^ sw));
    }
}

__device__ __forceinline__ void ldb_half(bf16x8* b, const u16* sb, int wc, int nh, int fr, int kq) {
    #pragma unroll
    for (int n = 0; n < 2; ++n) {
        int row = wc * 64 + (nh * 2 + n) * 16 + fr;
        int sw = (row & 4) << 2;
        #pragma unroll
        for (int ks = 0; ks < 2; ++ks)
            b[n * 2 + ks] = ds_read16(sb + row * 64 + ((ks * 32 + kq) ^ sw));
    }
}

__device__ __forceinline__ void mm_quad(f32x4* acc, const bf16x8* a, const bf16x8* b, int mh, int nh) {
    #pragma unroll
    for (int m = 0; m < 4; ++m)
        #pragma unroll
        for (int n = 0; n < 2; ++n) {
            int ia = mh * 4 + m;
            int ic = ia * 4 + nh * 2 + n;
            f32x4 c = acc[ic];
            c = __builtin_amdgcn_mfma_f32_16x16x32_bf16(a[ia * 2 + 0], b[n * 2 + 0], c, 0, 0, 0);
            c = __builtin_amdgcn_mfma_f32_16x16x32_bf16(a[ia * 2 + 1], b[n * 2 + 1], c, 0, 0, 0);
            acc[ic] = c;
        }
}

#define STAGEA(SAb, half, kt) stage2(Ag + (size_t)((half)*128)*K + (size_t)(kt)*64, SAb + (half)*8192 + wid*512, K)
#define STAGEB(SBb, half, kt) stage2(Bg + (size_t)((half)*128)*K + (size_t)(kt)*64, SBb + (half)*8192 + wid*512, K)
#define MMQ(mh, nh) do { WAITLGKM0(); __builtin_amdgcn_s_setprio(1); \
    mm_quad(acc, a, b, mh, nh); __builtin_amdgcn_s_setprio(0); } while (0)

template<int BIAS, int RELU>
__global__ __launch_bounds__(512, 2) void gemm256(
    const u16* __restrict__ A, const u16* __restrict__ Bt,
    const float* __restrict__ bias, u16* __restrict__ C,
    int M, int N, int K)
{
    __shared__ u16 S[65536];   // 128 KB
    const int tid  = threadIdx.x;
    const int lane = tid & 63;
    const int wid  = tid >> 6;
    const int wr   = wid >> 2, wc = wid & 3;
    const int fr   = lane & 15;
    const int grp  = lane >> 4;
    const int kq   = grp * 8;

    const int nbn = N >> 8;
    const int nwg = gridDim.x;
    const int cpx = nwg >> 3;
    const int bid = blockIdx.x;
    const int swz = (bid & 7) * cpx + (bid >> 3);
    const int bm  = (swz / nbn) * 256;
    const int bn  = (swz % nbn) * 256;

    const int srow = tid >> 3;
    const int scol = ((tid & 7) * 8) ^ (((tid >> 5) & 1) << 4);
    const u16* Ag = A  + (size_t)(bm + srow) * K + scol;
    const u16* Bg = Bt + (size_t)(bn + srow) * K + scol;

    u16* SA0 = S;
    u16* SA1 = S + 16384;
    u16* SB0 = S + 32768;
    u16* SB1 = S + 49152;

    f32x4 acc[32];
    #pragma unroll
    for (int i = 0; i < 32; ++i) acc[i] = (f32x4){0.f, 0.f, 0.f, 0.f};
    bf16x8 a[16], b[4];

    // prologue: K-tile0 full -> buf0, K-tile1 A-halves -> buf1
    STAGEA(SA0, 0, 0); STAGEA(SA0, 1, 0);
    STAGEB(SB0, 0, 0); STAGEB(SB0, 1, 0);
    STAGEA(SA1, 0, 1); STAGEA(SA1, 1, 1);
    WAITVM4();
    BARR();

    const int nt2 = K >> 7;
    for (int it = 0; it < nt2; ++it) {
        const bool last = (it == nt2 - 1);
        const int j0 = it * 2;
        // phase 1
        lda_half(a, SA0, wr, 0, fr, kq);
        ldb_half(b, SB0, wc, 0, fr, kq);
        STAGEB(SB1, 0, j0 + 1);
        BARR();
        MMQ(0, 0);
        BARR();
        // phase 2
        lda_half(a, SA0, wr, 1, fr, kq);
        STAGEB(SB1, 1, j0 + 1);
        BARR();
        MMQ(1, 0);
        BARR();
        // phase 3
        ldb_half(b, SB0, wc, 1, fr, kq);
        if (!last) STAGEA(SA0, 0, j0 + 2);
        BARR();
        MMQ(0, 1);
        BARR();
        // phase 4
        if (!last) STAGEA(SA0, 1, j0 + 2);
        BARR();
        MMQ(1, 1);
        if (last) { WAITVM0(); } else { WAITVM4(); }
        BARR();
        // phase 5
        lda_half(a, SA1, wr, 0, fr, kq);
        ldb_half(b, SB1, wc, 0, fr, kq);
        if (!last) STAGEB(SB0, 0, j0 + 2);
        BARR();
        MMQ(0, 0);
        BARR();
        // phase 6
        lda_half(a, SA1, wr, 1, fr, kq);
        if (!last) STAGEB(SB0, 1, j0 + 2);
        BARR();
        MMQ(1, 0);
        BARR();
        // phase 7
        ldb_half(b, SB1, wc, 1, fr, kq);
        if (!last) STAGEA(SA1, 0, j0 + 3);
        BARR();
        MMQ(0, 1);
        BARR();
        // phase 8
        if (!last) STAGEA(SA1, 1, j0 + 3);
        BARR();
        MMQ(1, 1);
        if (!last) { WAITVM4(); }
        BARR();
    }

    float bb[4] = {0.f, 0.f, 0.f, 0.f};
    if (BIAS) {
        #pragma unroll
        for (int n = 0; n < 4; ++n) bb[n] = bias[bn + wc * 64 + n * 16 + fr];
    }
    #pragma unroll
    for (int m = 0; m < 8; ++m) {
        #pragma unroll
        for (int n = 0; n < 4; ++n) {
            int col = bn + wc * 64 + n * 16 + fr;
            #pragma unroll
            for (int j = 0; j < 4; ++j) {
                int row = bm + wr * 128 + m * 16 + grp * 4 + j;
                float v = acc[m * 4 + n][j];
                if (BIAS) v += bb[n];
                if (RELU) v = fmaxf(v, 0.f);
                C[(size_t)row * N + col] = f2b(v);
            }
        }
    }
}

// ------------------------------------------------- attention (MFMA, 1 wave/token)
__global__ __launch_bounds__(256) void attn_mfma(
    const u16* __restrict__ QKV, const int* __restrict__ pad,
    u16* __restrict__ O)
{
    constexpr int WLDS = 6208;
    __shared__ u16 sh[4 * WLDS];
    const int wid  = threadIdx.x >> 6;
    const int lane = threadIdx.x & 63;
    const int site = blockIdx.x * 4 + wid;
    u16* Ql = sh + wid * WLDS;
    u16* Kl = Ql + 512;
    u16* Vl = Ql + 1024;
    u16* P  = Ql + 1600;
    u16* Ol = Ql + 5696;

    const u16* base = QKV + (size_t)site * 1536;
    *(bf16x8*)(Ql + lane * 8) = *(const bf16x8*)(base + lane * 8);
    *(bf16x8*)(Kl + lane * 8) = *(const bf16x8*)(base + 512 + lane * 8);
    {
        bf16x8 v = *(const bf16x8*)(base + 1024 + lane * 8);
        *(bf16x8*)(Vl + (lane >> 3) * 72 + (lane & 7) * 8) = v;
    }

    const int fr  = lane & 15;
    const int grp = lane >> 4;
    const bool masked = (pad[site] == 0);
    const bf16x8 zb = {0,0,0,0,0,0,0,0};
    const f32x4  zf = {0.f,0.f,0.f,0.f};

    if (masked) {
        const u16 c = f2b(1.0f / 64.0f);
        bf16x8 cv = {(short)c,(short)c,(short)c,(short)c,(short)c,(short)c,(short)c,(short)c};
        #pragma unroll
        for (int i = 0; i < 8; ++i)
            *(bf16x8*)(P + i * 512 + lane * 8) = cv;
    } else {
        bf16x8 aq[4], bk[4];
        #pragma unroll
        for (int m = 0; m < 4; ++m) { aq[m] = zb; bk[m] = zb; }
        if (grp == 0) {
            #pragma unroll
            for (int m = 0; m < 4; ++m)
                #pragma unroll
                for (int j = 0; j < 8; ++j) {
                    aq[m][j] = (short)Ql[j * 64 + m * 16 + fr];
                    bk[m][j] = (short)Kl[j * 64 + m * 16 + fr];
                }
        }
        #pragma unroll
        for (int m = 0; m < 4; ++m) {
            f32x4 ev[4];
            #pragma unroll
            for (int n = 0; n < 4; ++n)
                ev[n] = __builtin_amdgcn_mfma_f32_16x16x32_bf16(aq[m], bk[n], zf, 0, 0, 0);
            #pragma unroll
            for (int j = 0; j < 4; ++j) {
                float v = fmaxf(fmaxf(ev[0][j], ev[1][j]), fmaxf(ev[2][j], ev[3][j]));
                v = fmaxf(v, __shfl_xor(v, 1));
                v = fmaxf(v, __shfl_xor(v, 2));
                v = fmaxf(v, __shfl_xor(v, 4));
                v = fmaxf(v, __shfl_xor(v, 8));
                float p0 = __expf((ev[0][j] - v) * 0.03125f);
                float p1 = __expf((ev[1][j] - v) * 0.03125f);
                float p2 = __expf((ev[2][j] - v) * 0.03125f);
                float p3 = __expf((ev[3][j] - v) * 0.03125f);
                float s = p0 + p1 + p2 + p3;
                s += __shfl_xor(s, 1);
                s += __shfl_xor(s, 2);
                s += __shfl_xor(s, 4);
                s += __shfl_xor(s, 8);
                float inv = 1.0f / s;
                int row = m * 16 + grp * 4 + j;
                int sw  = (row & 7) << 3;
                P[(row * 64 +  0 + fr) ^ sw] = f2b(p0 * inv);
                P[(row * 64 + 16 + fr) ^ sw] = f2b(p1 * inv);
                P[(row * 64 + 32 + fr) ^ sw] = f2b(p2 * inv);
                P[(row * 64 + 48 + fr) ^ sw] = f2b(p3 * inv);
            }
        }
    }

    bf16x8 bv[2];
    #pragma unroll
    for (int ks = 0; ks < 2; ++ks) {
        int kb = ks * 32 + grp * 8;
        bv[ks] = (fr < 8) ? *(const bf16x8*)(Vl + fr * 72 + kb) : zb;
    }
    f32x4 pv[4];
    #pragma unroll
    for (int m = 0; m < 4; ++m) pv[m] = zf;
    #pragma unroll
    for (int m = 0; m < 4; ++m) {
        #pragma unroll
        for (int ks = 0; ks < 2; ++ks) {
            int row = m * 16 + fr;
            int off = (row * 64 + ks * 32 + grp * 8) ^ ((row & 7) << 3);
            bf16x8 ap = *(const bf16x8*)(P + off);
            pv[m] = __builtin_amdgcn_mfma_f32_16x16x32_bf16(ap, bv[ks], pv[m], 0, 0, 0);
        }
    }
    #pragma unroll
    for (int m = 0; m < 4; ++m)
        #pragma unroll
        for (int j = 0; j < 4; ++j) {
            int row = m * 16 + grp * 4 + j;
            if (fr < 8) Ol[row * 8 + fr] = f2b(pv[m][j]);
        }
    bf16x8 o = *(const bf16x8*)(Ol + lane * 8);
    *(bf16x8*)(O + (size_t)site * DM + lane * 8) = o;
}

// ------------------------------------------------- residual add + layernorm (bf16)
__global__ __launch_bounds__(256) void add_ln_kernel(
    const u16* __restrict__ A, u16* __restrict__ H,
    const float* __restrict__ g, const float* __restrict__ b)
{
    int row  = blockIdx.x * 4 + (threadIdx.x >> 6);
    int lane = threadIdx.x & 63;
    const u16* a = A + (size_t)row * DM + lane * 8;
    u16* h = H + (size_t)row * DM + lane * 8;
    bf16x8 av = *(const bf16x8*)a;
    bf16x8 hv = *(const bf16x8*)h;
    float v[8];
    float s = 0.f;
    #pragma unroll
    for (int j = 0; j < 8; ++j) { v[j] = b2f((u16)av[j]) + b2f((u16)hv[j]); s += v[j]; }
    #pragma unroll
    for (int off = 32; off > 0; off >>= 1) s += __shfl_xor(s, off, 64);
    float mean = s * (1.0f / 512.0f);
    float var = 0.f;
    #pragma unroll
    for (int j = 0; j < 8; ++j) { float d = v[j] - mean; var += d * d; }
    #pragma unroll
    for (int off = 32; off > 0; off >>= 1) var += __shfl_xor(var, off, 64);
    float rstd = rsqrtf(var * (1.0f / 512.0f) + 1e-5f);
    bf16x8 ov;
    #pragma unroll
    for (int j = 0; j < 8; ++j) {
        int d = lane * 8 + j;
        ov[j] = (short)f2b((v[j] - mean) * rstd * g[d] + b[d]);
    }
    *(bf16x8*)h = ov;
}

// ------------------------------------------------- final projection
__global__ __launch_bounds__(256) void out_stage1(
    const u16* __restrict__ h, const float* __restrict__ W,
    float* __restrict__ partial)
{
    int b = blockIdx.x, s = blockIdx.y;
    int tid = threadIdx.x;
    const u16* hb = h + (size_t)b * (TSEQ * DM) + (size_t)s * 8192;
    const float* Wb = W + (size_t)s * 8192 * 3;
    float a0 = 0.f, a1 = 0.f, a2 = 0.f;
    #pragma unroll 4
    for (int it = 0; it < 32; ++it) {
        int i = it * 256 + tid;
        float hv = b2f(hb[i]);
        a0 += hv * Wb[i * 3 + 0];
        a1 += hv * Wb[i * 3 + 1];
        a2 += hv * Wb[i * 3 + 2];
    }
    __shared__ float red[3][256];
    red[0][tid] = a0; red[1][tid] = a1; red[2][tid] = a2;
    __syncthreads();
    for (int off = 128; off > 0; off >>= 1) {
        if (tid < off) {
            red[0][tid] += red[0][tid + off];
            red[1][tid] += red[1][tid + off];
            red[2][tid] += red[2][tid + off];
        }
        __syncthreads();
    }
    if (tid == 0) {
        partial[(b * 64 + s) * 3 + 0] = red[0][0];
        partial[(b * 64 + s) * 3 + 1] = red[1][0];
        partial[(b * 64 + s) * 3 + 2] = red[2][0];
    }
}

__global__ __launch_bounds__(64) void out_stage2(
    const float* __restrict__ partial, const float* __restrict__ ob,
    float* __restrict__ out)
{
    int t = threadIdx.x;
    if (t < NB * DOUTN) {
        int b = t / 3, o = t % 3;
        float s = ob[o];
        for (int k = 0; k < 64; ++k) s += partial[(b * 64 + k) * 3 + o];
        out[t] = s;
    }
}

// ------------------------------------------------- launch
extern "C" void kernel_launch(void* const* d_in, const int* in_sizes, int n_in,
                              void* d_out, int out_size, void* d_ws, size_t ws_size,
                              hipStream_t stream)
{
    const float* x    = (const float*)d_in[0];
    const int*   pad  = (const int*)  d_in[1];
    const float* encW = (const float*)d_in[2];
    const float* encB = (const float*)d_in[3];
    const float* Wq   = (const float*)d_in[4];
    const float* Wk   = (const float*)d_in[5];
    const float* Wv   = (const float*)d_in[6];
    const float* Wo   = (const float*)d_in[7];
    const float* fW1  = (const float*)d_in[8];
    const float* fb1  = (const float*)d_in[9];
    const float* fW2  = (const float*)d_in[10];
    const float* fb2  = (const float*)d_in[11];
    const float* l1g  = (const float*)d_in[12];
    const float* l1b  = (const float*)d_in[13];
    const float* l2g  = (const float*)d_in[14];
    const float* l2b  = (const float*)d_in[15];
    const float* outW = (const float*)d_in[16];
    const float* outB = (const float*)d_in[17];
    float* out = (float*)d_out;

    const size_t WL  = 3145728;
    const size_t BUF = (size_t)ROWS * DM;
    const size_t need = (4 * WL + 6 * BUF) * sizeof(u16);
    if (ws_size < need) return;
    u16* wt = (u16*)d_ws;
    u16* h  = wt + 4 * WL;
    u16* b0 = h  + BUF;
    u16* b3 = b0 + 3 * BUF;
    u16* b4 = b3 + BUF;

    transpose_cast<<<dim3(16,16,4), 256, 0, stream>>>(Wq,  wt + 0,       512,  512,  (size_t)512*512,  WL);
    transpose_cast<<<dim3(16,16,4), 256, 0, stream>>>(Wk,  wt + 262144,  512,  512,  (size_t)512*512,  WL);
    transpose_cast<<<dim3(16,16,4), 256, 0, stream>>>(Wv,  wt + 524288,  512,  512,  (size_t)512*512,  WL);
    transpose_cast<<<dim3(16,16,4), 256, 0, stream>>>(Wo,  wt + 786432,  512,  512,  (size_t)512*512,  WL);
    transpose_cast<<<dim3(16,64,4), 256, 0, stream>>>(fW1, wt + 1048576, 512,  2048, (size_t)512*2048, WL);
    transpose_cast<<<dim3(64,16,4), 256, 0, stream>>>(fW2, wt + 2097152, 2048, 512,  (size_t)2048*512, WL);

    encode_kernel<<<ROWS, 128, 0, stream>>>(x, pad, encW, encB, h);

    for (int l = 0; l < NLAYERS; ++l) {
        u16* wl = wt + (size_t)l * WL;
        // QKV fused (N=1536): 8-phase 256^2, 384 blocks
        gemm256<0,0><<<dim3((ROWS/256)*(1536/256)), 512, 0, stream>>>(h, wl, nullptr, b0, ROWS, 1536, DM);
        attn_mfma<<<ROWS/4, 256, 0, stream>>>(b0, pad, b3);
        // Wo (N=512): 128^2, 512 blocks (machine-filling)
        gemm_bf16<0,0><<<dim3(128,4), 256, 0, stream>>>(b3, wl + 786432, nullptr, b4, ROWS, DM, DM);
        add_ln_kernel<<<ROWS/4, 256, 0, stream>>>(b4, h, l1g + l*DM, l1b + l*DM);
        // FF1 (N=2048): 8-phase 256^2, 512 blocks
        gemm256<1,1><<<dim3((ROWS/256)*(DFFN/256)), 512, 0, stream>>>(h, wl + 1048576, fb1 + (size_t)l*DFFN, b0, ROWS, DFFN, DM);
        // FF2 (N=512): 128^2, 512 blocks
        gemm_bf16<1,0><<<dim3(128,4), 256, 0, stream>>>(b0, wl + 2097152, fb2 + (size_t)l*DM, b4, ROWS, DM, DFFN);
        add_ln_kernel<<<ROWS/4, 256, 0, stream>>>(b4, h, l2g + l*DM, l2b + l*DM);
    }

    out_stage1<<<dim3(NB, 64), 256, 0, stream>>>(h, outW, (float*)b0);
    out_stage2<<<1, 64, 0, stream>>>((float*)b0, outB, out);
}

// Round 6
// 852.779 us; speedup vs baseline: 1.2427x; 1.2427x over previous
//
#include <hip/hip_runtime.h>
#include <cmath>

#define NB 16
#define TSEQ 1024
#define DIN 16
#define DM 512
#define DFFN 2048
#define NLAYERS 4
#define DOUTN 3
#define ROWS (NB*TSEQ)   /* 16384 */

typedef unsigned short u16;
typedef short bf16x8 __attribute__((ext_vector_type(8)));
typedef u16   u16x4  __attribute__((ext_vector_type(4)));
typedef float f32x4  __attribute__((ext_vector_type(4)));

__device__ __forceinline__ float b2f(u16 v) { return __uint_as_float((unsigned)v << 16); }
__device__ __forceinline__ u16 f2b(float f) {
    unsigned u = __float_as_uint(f);
    return (u16)((u + 0x7FFFu + ((u >> 16) & 1u)) >> 16);
}

#define GLL(gp, lp) __builtin_amdgcn_global_load_lds( \
    (const __attribute__((address_space(1))) unsigned int*)(gp), \
    (__attribute__((address_space(3))) unsigned int*)(lp), 16, 0, 0)

// ------------------------------------------------- weight transpose + cast
__global__ __launch_bounds__(256) void transpose_cast(
    const float* __restrict__ in, u16* __restrict__ out,
    int K, int N, size_t in_lstride, size_t out_lstride)
{
    in  += (size_t)blockIdx.z * in_lstride;
    out += (size_t)blockIdx.z * out_lstride;
    __shared__ float t[32][33];
    int bk = blockIdx.x * 32, bn = blockIdx.y * 32;
    int x = threadIdx.x & 31, y = threadIdx.x >> 5;
    #pragma unroll
    for (int i = 0; i < 32; i += 8)
        t[y + i][x] = in[(size_t)(bk + y + i) * N + bn + x];
    __syncthreads();
    #pragma unroll
    for (int i = 0; i < 32; i += 8)
        out[(size_t)(bn + y + i) * K + bk + x] = f2b(t[x][y + i]);
}

// ------------------------------------------------- encode (bf16 out)
__global__ __launch_bounds__(128) void encode_kernel(
    const float* __restrict__ x, const int* __restrict__ pad,
    const float* __restrict__ W, const float* __restrict__ b,
    u16* __restrict__ h)
{
    int row = blockIdx.x;
    int t   = row & (TSEQ - 1);
    int c   = threadIdx.x * 4;
    float acc[4];
    #pragma unroll
    for (int j = 0; j < 4; ++j) acc[j] = b[c + j];
    const float* xr = x + (size_t)row * DIN;
    #pragma unroll
    for (int k = 0; k < DIN; ++k) {
        float xv = xr[k];
        const float* wr = W + (size_t)k * DM + c;
        #pragma unroll
        for (int j = 0; j < 4; ++j) acc[j] += xv * wr[j];
    }
    const float s = 22.62741699796952f;
    bool has_pe = (pad[row] != 0);
    u16x4 o;
    #pragma unroll
    for (int j = 0; j < 4; ++j) {
        acc[j] *= s;
        if (has_pe) {
            int d = c + j;
            float base = (float)t * powf(10000.0f, -(float)d * (1.0f/512.0f));
            acc[j] += ((d & 1) == 0) ? sinf(base) : cosf(base);
        }
        o[j] = f2b(acc[j]);
    }
    *(u16x4*)&h[(size_t)row * DM + c] = o;
}

// ------------------------------------------------- 128x128 MFMA GEMM, BK=64 + G4 swizzle
// C(MxN) = A(MxK) @ Bt(NxK)^T [+bias] [relu].  256 thr = 4 waves (2x2), 64x64/wave.
// LDS [128 rows][64 cols] per matrix (32KB total); 16B chunk c of row r stored at
// slot c^(r&7) via pre-swizzled GLOBAL source col (GLL dest linear, rule #21);
// fragment reads apply the same XOR -> 2-way conflicts (free).
template<int BIAS, int RELU>
__global__ __launch_bounds__(256) void gemm_bf16(
    const u16* __restrict__ A, const u16* __restrict__ Bt,
    const float* __restrict__ bias, u16* __restrict__ C,
    int M, int N, int K)
{
    __shared__ u16 As[128 * 64];
    __shared__ u16 Bs[128 * 64];
    const int tid  = threadIdx.x;
    const int lane = tid & 63;
    const int wid  = tid >> 6;
    const int wr   = wid >> 1, wc = wid & 1;
    const int bm   = blockIdx.x * 128;
    const int bn   = blockIdx.y * 128;

    // staging: wave w stages rows w*32..w*32+31 of each tile, 4 GLLs per matrix.
    // lane -> row-in-8 = lane>>3, slot = lane&7; source chunk = slot ^ row8.
    const int srow8 = lane >> 3;
    const int sslot = lane & 7;
    const int scol  = ((sslot ^ srow8) * 8);
    const u16* Ag = A  + (size_t)(bm + wid * 32 + srow8) * K + scol;
    const u16* Bg = Bt + (size_t)(bn + wid * 32 + srow8) * K + scol;
    u16* Al = As + wid * 2048;   // 32 rows * 64
    u16* Bl = Bs + wid * 2048;

    f32x4 acc[4][4];
    #pragma unroll
    for (int m = 0; m < 4; ++m)
        #pragma unroll
        for (int n = 0; n < 4; ++n)
            acc[m][n] = (f32x4){0.f, 0.f, 0.f, 0.f};

    const int fr  = lane & 15;
    const int grp = lane >> 4;

    for (int k0 = 0; k0 < K; k0 += 64) {
        #pragma unroll
        for (int i = 0; i < 4; ++i) {
            GLL(Ag + (size_t)(i * 8) * K + k0, Al + i * 512);
            GLL(Bg + (size_t)(i * 8) * K + k0, Bl + i * 512);
        }
        __syncthreads();
        bf16x8 a[4][2];
        #pragma unroll
        for (int m = 0; m < 4; ++m) {
            int row = wr * 64 + m * 16 + fr;
            #pragma unroll
            for (int ks = 0; ks < 2; ++ks) {
                int slot = (ks * 4 + grp) ^ (row & 7);
                a[m][ks] = *(const bf16x8*)(As + row * 64 + slot * 8);
            }
        }
        #pragma unroll
        for (int n = 0; n < 4; ++n) {
            bf16x8 b[2];
            int row = wc * 64 + n * 16 + fr;
            #pragma unroll
            for (int ks = 0; ks < 2; ++ks) {
                int slot = (ks * 4 + grp) ^ (row & 7);
                b[ks] = *(const bf16x8*)(Bs + row * 64 + slot * 8);
            }
            #pragma unroll
            for (int m = 0; m < 4; ++m) {
                acc[m][n] = __builtin_amdgcn_mfma_f32_16x16x32_bf16(a[m][0], b[0], acc[m][n], 0, 0, 0);
                acc[m][n] = __builtin_amdgcn_mfma_f32_16x16x32_bf16(a[m][1], b[1], acc[m][n], 0, 0, 0);
            }
        }
        __syncthreads();
    }

    float bb[4] = {0.f, 0.f, 0.f, 0.f};
    if (BIAS) {
        #pragma unroll
        for (int n = 0; n < 4; ++n) bb[n] = bias[bn + wc * 64 + n * 16 + fr];
    }
    #pragma unroll
    for (int m = 0; m < 4; ++m) {
        #pragma unroll
        for (int n = 0; n < 4; ++n) {
            int col = bn + wc * 64 + n * 16 + fr;
            #pragma unroll
            for (int j = 0; j < 4; ++j) {
                int row = bm + wr * 64 + m * 16 + ((lane >> 4) << 2) + j;
                float v = acc[m][n][j];
                if (BIAS) v += bb[n];
                if (RELU) v = fmaxf(v, 0.f);
                C[(size_t)row * N + col] = f2b(v);
            }
        }
    }
}

// ------------------------------------------------- attention (MFMA, 1 wave/token)
__global__ __launch_bounds__(256) void attn_mfma(
    const u16* __restrict__ QKV, const int* __restrict__ pad,
    u16* __restrict__ O)
{
    constexpr int WLDS = 6208;
    __shared__ u16 sh[4 * WLDS];
    const int wid  = threadIdx.x >> 6;
    const int lane = threadIdx.x & 63;
    const int site = blockIdx.x * 4 + wid;
    u16* Ql = sh + wid * WLDS;
    u16* Kl = Ql + 512;
    u16* Vl = Ql + 1024;
    u16* P  = Ql + 1600;
    u16* Ol = Ql + 5696;

    const u16* base = QKV + (size_t)site * 1536;
    *(bf16x8*)(Ql + lane * 8) = *(const bf16x8*)(base + lane * 8);
    *(bf16x8*)(Kl + lane * 8) = *(const bf16x8*)(base + 512 + lane * 8);
    {
        bf16x8 v = *(const bf16x8*)(base + 1024 + lane * 8);
        *(bf16x8*)(Vl + (lane >> 3) * 72 + (lane & 7) * 8) = v;
    }

    const int fr  = lane & 15;
    const int grp = lane >> 4;
    const bool masked = (pad[site] == 0);
    const bf16x8 zb = {0,0,0,0,0,0,0,0};
    const f32x4  zf = {0.f,0.f,0.f,0.f};

    if (masked) {
        const u16 c = f2b(1.0f / 64.0f);
        bf16x8 cv = {(short)c,(short)c,(short)c,(short)c,(short)c,(short)c,(short)c,(short)c};
        #pragma unroll
        for (int i = 0; i < 8; ++i)
            *(bf16x8*)(P + i * 512 + lane * 8) = cv;
    } else {
        bf16x8 aq[4], bk[4];
        #pragma unroll
        for (int m = 0; m < 4; ++m) { aq[m] = zb; bk[m] = zb; }
        if (grp == 0) {
            #pragma unroll
            for (int m = 0; m < 4; ++m)
                #pragma unroll
                for (int j = 0; j < 8; ++j) {
                    aq[m][j] = (short)Ql[j * 64 + m * 16 + fr];
                    bk[m][j] = (short)Kl[j * 64 + m * 16 + fr];
                }
        }
        #pragma unroll
        for (int m = 0; m < 4; ++m) {
            f32x4 ev[4];
            #pragma unroll
            for (int n = 0; n < 4; ++n)
                ev[n] = __builtin_amdgcn_mfma_f32_16x16x32_bf16(aq[m], bk[n], zf, 0, 0, 0);
            #pragma unroll
            for (int j = 0; j < 4; ++j) {
                float v = fmaxf(fmaxf(ev[0][j], ev[1][j]), fmaxf(ev[2][j], ev[3][j]));
                v = fmaxf(v, __shfl_xor(v, 1));
                v = fmaxf(v, __shfl_xor(v, 2));
                v = fmaxf(v, __shfl_xor(v, 4));
                v = fmaxf(v, __shfl_xor(v, 8));
                float p0 = __expf((ev[0][j] - v) * 0.03125f);
                float p1 = __expf((ev[1][j] - v) * 0.03125f);
                float p2 = __expf((ev[2][j] - v) * 0.03125f);
                float p3 = __expf((ev[3][j] - v) * 0.03125f);
                float s = p0 + p1 + p2 + p3;
                s += __shfl_xor(s, 1);
                s += __shfl_xor(s, 2);
                s += __shfl_xor(s, 4);
                s += __shfl_xor(s, 8);
                float inv = 1.0f / s;
                int row = m * 16 + grp * 4 + j;
                int sw  = (row & 7) << 3;
                P[(row * 64 +  0 + fr) ^ sw] = f2b(p0 * inv);
                P[(row * 64 + 16 + fr) ^ sw] = f2b(p1 * inv);
                P[(row * 64 + 32 + fr) ^ sw] = f2b(p2 * inv);
                P[(row * 64 + 48 + fr) ^ sw] = f2b(p3 * inv);
            }
        }
    }

    bf16x8 bv[2];
    #pragma unroll
    for (int ks = 0; ks < 2; ++ks) {
        int kb = ks * 32 + grp * 8;
        bv[ks] = (fr < 8) ? *(const bf16x8*)(Vl + fr * 72 + kb) : zb;
    }
    f32x4 pv[4];
    #pragma unroll
    for (int m = 0; m < 4; ++m) pv[m] = zf;
    #pragma unroll
    for (int m = 0; m < 4; ++m) {
        #pragma unroll
        for (int ks = 0; ks < 2; ++ks) {
            int row = m * 16 + fr;
            int off = (row * 64 + ks * 32 + grp * 8) ^ ((row & 7) << 3);
            bf16x8 ap = *(const bf16x8*)(P + off);
            pv[m] = __builtin_amdgcn_mfma_f32_16x16x32_bf16(ap, bv[ks], pv[m], 0, 0, 0);
        }
    }
    #pragma unroll
    for (int m = 0; m < 4; ++m)
        #pragma unroll
        for (int j = 0; j < 4; ++j) {
            int row = m * 16 + grp * 4 + j;
            if (fr < 8) Ol[row * 8 + fr] = f2b(pv[m][j]);
        }
    bf16x8 o = *(const bf16x8*)(Ol + lane * 8);
    *(bf16x8*)(O + (size_t)site * DM + lane * 8) = o;
}

// ------------------------------------------------- residual add + layernorm (bf16)
__global__ __launch_bounds__(256) void add_ln_kernel(
    const u16* __restrict__ A, u16* __restrict__ H,
    const float* __restrict__ g, const float* __restrict__ b)
{
    int row  = blockIdx.x * 4 + (threadIdx.x >> 6);
    int lane = threadIdx.x & 63;
    const u16* a = A + (size_t)row * DM + lane * 8;
    u16* h = H + (size_t)row * DM + lane * 8;
    bf16x8 av = *(const bf16x8*)a;
    bf16x8 hv = *(const bf16x8*)h;
    float v[8];
    float s = 0.f;
    #pragma unroll
    for (int j = 0; j < 8; ++j) { v[j] = b2f((u16)av[j]) + b2f((u16)hv[j]); s += v[j]; }
    #pragma unroll
    for (int off = 32; off > 0; off >>= 1) s += __shfl_xor(s, off, 64);
    float mean = s * (1.0f / 512.0f);
    float var = 0.f;
    #pragma unroll
    for (int j = 0; j < 8; ++j) { float d = v[j] - mean; var += d * d; }
    #pragma unroll
    for (int off = 32; off > 0; off >>= 1) var += __shfl_xor(var, off, 64);
    float rstd = rsqrtf(var * (1.0f / 512.0f) + 1e-5f);
    bf16x8 ov;
    #pragma unroll
    for (int j = 0; j < 8; ++j) {
        int d = lane * 8 + j;
        ov[j] = (short)f2b((v[j] - mean) * rstd * g[d] + b[d]);
    }
    *(bf16x8*)h = ov;
}

// ------------------------------------------------- final projection
__global__ __launch_bounds__(256) void out_stage1(
    const u16* __restrict__ h, const float* __restrict__ W,
    float* __restrict__ partial)
{
    int b = blockIdx.x, s = blockIdx.y;
    int tid = threadIdx.x;
    const u16* hb = h + (size_t)b * (TSEQ * DM) + (size_t)s * 8192;
    const float* Wb = W + (size_t)s * 8192 * 3;
    float a0 = 0.f, a1 = 0.f, a2 = 0.f;
    #pragma unroll 4
    for (int it = 0; it < 32; ++it) {
        int i = it * 256 + tid;
        float hv = b2f(hb[i]);
        a0 += hv * Wb[i * 3 + 0];
        a1 += hv * Wb[i * 3 + 1];
        a2 += hv * Wb[i * 3 + 2];
    }
    __shared__ float red[3][256];
    red[0][tid] = a0; red[1][tid] = a1; red[2][tid] = a2;
    __syncthreads();
    for (int off = 128; off > 0; off >>= 1) {
        if (tid < off) {
            red[0][tid] += red[0][tid + off];
            red[1][tid] += red[1][tid + off];
            red[2][tid] += red[2][tid + off];
        }
        __syncthreads();
    }
    if (tid == 0) {
        partial[(b * 64 + s) * 3 + 0] = red[0][0];
        partial[(b * 64 + s) * 3 + 1] = red[1][0];
        partial[(b * 64 + s) * 3 + 2] = red[2][0];
    }
}

__global__ __launch_bounds__(64) void out_stage2(
    const float* __restrict__ partial, const float* __restrict__ ob,
    float* __restrict__ out)
{
    int t = threadIdx.x;
    if (t < NB * DOUTN) {
        int b = t / 3, o = t % 3;
        float s = ob[o];
        for (int k = 0; k < 64; ++k) s += partial[(b * 64 + k) * 3 + o];
        out[t] = s;
    }
}

// ------------------------------------------------- launch
extern "C" void kernel_launch(void* const* d_in, const int* in_sizes, int n_in,
                              void* d_out, int out_size, void* d_ws, size_t ws_size,
                              hipStream_t stream)
{
    const float* x    = (const float*)d_in[0];
    const int*   pad  = (const int*)  d_in[1];
    const float* encW = (const float*)d_in[2];
    const float* encB = (const float*)d_in[3];
    const float* Wq   = (const float*)d_in[4];
    const float* Wk   = (const float*)d_in[5];
    const float* Wv   = (const float*)d_in[6];
    const float* Wo   = (const float*)d_in[7];
    const float* fW1  = (const float*)d_in[8];
    const float* fb1  = (const float*)d_in[9];
    const float* fW2  = (const float*)d_in[10];
    const float* fb2  = (const float*)d_in[11];
    const float* l1g  = (const float*)d_in[12];
    const float* l1b  = (const float*)d_in[13];
    const float* l2g  = (const float*)d_in[14];
    const float* l2b  = (const float*)d_in[15];
    const float* outW = (const float*)d_in[16];
    const float* outB = (const float*)d_in[17];
    float* out = (float*)d_out;

    const size_t WL  = 3145728;
    const size_t BUF = (size_t)ROWS * DM;
    const size_t need = (4 * WL + 6 * BUF) * sizeof(u16);
    if (ws_size < need) return;
    u16* wt = (u16*)d_ws;
    u16* h  = wt + 4 * WL;
    u16* b0 = h  + BUF;
    u16* b3 = b0 + 3 * BUF;
    u16* b4 = b3 + BUF;

    transpose_cast<<<dim3(16,16,4), 256, 0, stream>>>(Wq,  wt + 0,       512,  512,  (size_t)512*512,  WL);
    transpose_cast<<<dim3(16,16,4), 256, 0, stream>>>(Wk,  wt + 262144,  512,  512,  (size_t)512*512,  WL);
    transpose_cast<<<dim3(16,16,4), 256, 0, stream>>>(Wv,  wt + 524288,  512,  512,  (size_t)512*512,  WL);
    transpose_cast<<<dim3(16,16,4), 256, 0, stream>>>(Wo,  wt + 786432,  512,  512,  (size_t)512*512,  WL);
    transpose_cast<<<dim3(16,64,4), 256, 0, stream>>>(fW1, wt + 1048576, 512,  2048, (size_t)512*2048, WL);
    transpose_cast<<<dim3(64,16,4), 256, 0, stream>>>(fW2, wt + 2097152, 2048, 512,  (size_t)2048*512, WL);

    encode_kernel<<<ROWS, 128, 0, stream>>>(x, pad, encW, encB, h);

    for (int l = 0; l < NLAYERS; ++l) {
        u16* wl = wt + (size_t)l * WL;
        gemm_bf16<0,0><<<dim3(128,12), 256, 0, stream>>>(h, wl, nullptr, b0, ROWS, 1536, DM);
        attn_mfma<<<ROWS/4, 256, 0, stream>>>(b0, pad, b3);
        gemm_bf16<0,0><<<dim3(128,4), 256, 0, stream>>>(b3, wl + 786432, nullptr, b4, ROWS, DM, DM);
        add_ln_kernel<<<ROWS/4, 256, 0, stream>>>(b4, h, l1g + l*DM, l1b + l*DM);
        gemm_bf16<1,1><<<dim3(128,16), 256, 0, stream>>>(h, wl + 1048576, fb1 + (size_t)l*DFFN, b0, ROWS, DFFN, DM);
        gemm_bf16<1,0><<<dim3(128,4),  256, 0, stream>>>(b0, wl + 2097152, fb2 + (size_t)l*DM, b4, ROWS, DM, DFFN);
        add_ln_kernel<<<ROWS/4, 256, 0, stream>>>(b4, h, l2g + l*DM, l2b + l*DM);
    }

    out_stage1<<<dim3(NB, 64), 256, 0, stream>>>(h, outW, (float*)b0);
    out_stage2<<<1, 64, 0, stream>>>((float*)b0, outB, out);
}